// Round 3
// baseline (2215.260 us; speedup 1.0000x reference)
//
#include <hip/hip_runtime.h>

#define NB 16
#define NC 256
#define NH 64
#define NW 64
#define NK 1024
#define HW (NH * NW)          // 4096
#define NPOS (NB * HW)        // 65536
#define NOUT (NB * NC * HW)   // 16777216

__device__ __forceinline__ float sq_rn(float x) { return __fmul_rn(x, x); }

// Exact replica of numpy pairwise_sum for sum(a*a) over n=256 elements with
// given element stride: n=256 > PW_BLOCKSIZE(128) -> split 128+128; each
// 128-half uses 8 accumulators r[0..7], combined
// ((r0+r1)+(r2+r3))+((r4+r5)+(r6+r7)); halves joined by one add. Squares
// rounded before summing (no FMA) — matches numpy's zf*zf temp + np.sum.
__device__ __forceinline__ float pairwise_sumsq_256(const float* __restrict__ a,
                                                    int stride) {
    float s_half[2];
#pragma unroll
    for (int h = 0; h < 2; ++h) {
        const float* base = a + (size_t)(h * 128) * stride;
        float r[8];
#pragma unroll
        for (int j = 0; j < 8; ++j) r[j] = sq_rn(base[(size_t)j * stride]);
        for (int i = 8; i < 128; i += 8) {
#pragma unroll
            for (int j = 0; j < 8; ++j)
                r[j] = __fadd_rn(r[j], sq_rn(base[(size_t)(i + j) * stride]));
        }
        s_half[h] = __fadd_rn(
            __fadd_rn(__fadd_rn(r[0], r[1]), __fadd_rn(r[2], r[3])),
            __fadd_rn(__fadd_rn(r[4], r[5]), __fadd_rn(r[6], r[7])));
    }
    return __fadd_rn(s_half[0], s_half[1]);
}

// ---------------------------------------------------------------------------
// Kernel A: cnorm[k] = numpy-fp32 sum(codebook[k]^2)
// ---------------------------------------------------------------------------
__global__ __launch_bounds__(256) void cnorm_kernel(const float* __restrict__ cb,
                                                    float* __restrict__ cnorm) {
    int k = blockIdx.x * 256 + threadIdx.x;
    if (k < NK) {
        cnorm[k] = pairwise_sumsq_256(cb + (size_t)k * NC, 1);
    }
}

// ---------------------------------------------------------------------------
// Kernel B: per position p, argmin_k fl32( fl32(znorm + cnorm_k) - 2*dot ),
// dot = single sequential fp32-FMA chain over ascending c (bit-exact vs BLAS,
// verified R2). Grid: 1024 blocks = (b,h). Block: 4 waves; wave = 256-code
// quarter, lane = w position. K-tile 32 (8 passes).
// Codebook base is laundered through __shfl so addresses look divergent ->
// VMEM broadcast loads (VGPR path, deep vmcnt pipelining) instead of the
// SGPR-starved s_load path that serialized at lgkmcnt(0) (R2: VALUBusy 47%).
// ---------------------------------------------------------------------------
__global__ __launch_bounds__(256, 4) void argmin_kernel(const float* __restrict__ z,
                                                        const float* __restrict__ cb,
                                                        const float* __restrict__ cnorm,
                                                        int* __restrict__ idx_ws,
                                                        float* __restrict__ idx_out) {
    const int tile = blockIdx.x;      // 0..1023
    const int b = tile >> 6;          // 0..15
    const int h = tile & 63;          // 0..63
    const int lane = threadIdx.x & 63;
    const int wave = threadIdx.x >> 6;  // 0..3

    // z[((b*NC + c)*NH + h)*NW + w]; thread owns w = lane
    const float* zbase = z + (size_t)b * NC * HW + h * NW + lane;

    // numpy-exact ||z_p||^2 (pairwise order, stride HW across channels)
    const float znorm = pairwise_sumsq_256(zbase, HW);

    // Launder the wave-uniform code base: __shfl emits ds_bpermute whose
    // result the compiler treats as divergent -> codebook loads go to VMEM.
    const int kb = __shfl(wave * 256, 0);
    const float* cbw = cb + (size_t)kb * NC;

    float best = 3.4e38f;
    int bidx = 0;

    for (int pass = 0; pass < 8; ++pass) {
        const int kq0 = pass * 32;          // code offset within this quarter
        float acc[32];
#pragma unroll
        for (int i = 0; i < 32; ++i) acc[i] = 0.f;

        for (int c0 = 0; c0 < NC; c0 += 8) {
            float vz[8];
#pragma unroll
            for (int j = 0; j < 8; ++j) vz[j] = zbase[(size_t)(c0 + j) * HW];
#pragma unroll
            for (int kk = 0; kk < 32; ++kk) {
                const float4* cp =
                    (const float4*)(cbw + (size_t)(kq0 + kk) * NC + c0);
                const float4 ca = cp[0];
                const float4 cc = cp[1];
                float a = acc[kk];
                a = __fmaf_rn(vz[0], ca.x, a);
                a = __fmaf_rn(vz[1], ca.y, a);
                a = __fmaf_rn(vz[2], ca.z, a);
                a = __fmaf_rn(vz[3], ca.w, a);
                a = __fmaf_rn(vz[4], cc.x, a);
                a = __fmaf_rn(vz[5], cc.y, a);
                a = __fmaf_rn(vz[6], cc.z, a);
                a = __fmaf_rn(vz[7], cc.w, a);
                acc[kk] = a;
            }
        }

#pragma unroll
        for (int kk = 0; kk < 32; ++kk) {
            const int k = wave * 256 + kq0 + kk;
            // d = fl( fl(znorm + cnorm_k) - 2*dot_k )  -- reference fp32 order
            const float sc = __fsub_rn(__fadd_rn(znorm, cnorm[k]),
                                       __fmul_rn(2.0f, acc[kk]));
            // strict < with ascending k == np.argmin first-occurrence
            if (sc < best || (sc == best && k < bidx)) {
                best = sc;
                bidx = k;
            }
        }
    }

    __shared__ float sval[4][64];
    __shared__ int sidx[4][64];
    sval[wave][lane] = best;
    sidx[wave][lane] = bidx;
    __syncthreads();

    if (threadIdx.x < 64) {
        float bv = sval[0][lane];
        int bi = sidx[0][lane];
#pragma unroll
        for (int w = 1; w < 4; ++w) {
            float v = sval[w][lane];
            int i2 = sidx[w][lane];
            if (v < bv || (v == bv && i2 < bi)) {
                bv = v;
                bi = i2;
            }
        }
        const int pos = b * HW + h * NW + lane;
        idx_ws[pos] = bi;
        idx_out[pos] = (float)bi;   // indices output stored as float32
    }
}

// ---------------------------------------------------------------------------
// Kernel C: out[b,c,h,w] = cb[idx[b,h,w]][c]; accumulate sum((zq - z)^2)
// ---------------------------------------------------------------------------
__global__ __launch_bounds__(256) void gather_loss_kernel(const float* __restrict__ z,
                                                          const float* __restrict__ cb,
                                                          const int* __restrict__ idx_ws,
                                                          float* __restrict__ out,
                                                          double* __restrict__ loss_acc) {
    const unsigned g = blockIdx.x * 256u + threadIdx.x;  // float4 index
    const unsigned e = g * 4u;                           // element index
    const unsigned w = e & 63u;
    const unsigned h = (e >> 6) & 63u;
    const unsigned c = (e >> 12) & 255u;
    const unsigned b = e >> 20;

    const unsigned p = b * HW + h * NW + w;  // divisible by 4

    const int4 iv = *(const int4*)(idx_ws + p);
    const float4 z4 = *(const float4*)(z + e);

    float4 o;
    o.x = cb[(size_t)iv.x * NC + c];
    o.y = cb[(size_t)iv.y * NC + c];
    o.z = cb[(size_t)iv.z * NC + c];
    o.w = cb[(size_t)iv.w * NC + c];

    *(float4*)(out + e) = o;

    const float d0 = o.x - z4.x;
    const float d1 = o.y - z4.y;
    const float d2 = o.z - z4.z;
    const float d3 = o.w - z4.w;
    float part = d0 * d0 + d1 * d1 + d2 * d2 + d3 * d3;

#pragma unroll
    for (int off = 32; off > 0; off >>= 1) part += __shfl_down(part, off, 64);

    __shared__ float wsum[4];
    const int lane = threadIdx.x & 63;
    const int wave = threadIdx.x >> 6;
    if (lane == 0) wsum[wave] = part;
    __syncthreads();
    if (threadIdx.x == 0) {
        float s = wsum[0] + wsum[1] + wsum[2] + wsum[3];
        atomicAdd(loss_acc, (double)s);
    }
}

// ---------------------------------------------------------------------------
// Kernel D: loss = (1 + beta) * sum / NOUT
// ---------------------------------------------------------------------------
__global__ void finalize_kernel(const double* __restrict__ loss_acc,
                                float* __restrict__ out_loss) {
    if (threadIdx.x == 0) {
        *out_loss = (float)(1.25 * (*loss_acc) / (double)NOUT);
    }
}

extern "C" void kernel_launch(void* const* d_in, const int* in_sizes, int n_in,
                              void* d_out, int out_size, void* d_ws, size_t ws_size,
                              hipStream_t stream) {
    const float* z = (const float*)d_in[0];
    const float* cb = (const float*)d_in[1];

    float* out = (float*)d_out;            // [16,256,64,64]
    float* loss_out = out + NOUT;          // scalar
    float* idx_out = out + NOUT + 1;       // [16,1,64,64] as float

    double* loss_acc = (double*)d_ws;                      // 8 B (zeroed below)
    float* cnorm = (float*)((char*)d_ws + 64);             // 4 KB
    int* idx_ws = (int*)((char*)d_ws + 64 + NK * 4);       // 256 KB

    hipMemsetAsync(d_ws, 0, 64, stream);
    cnorm_kernel<<<(NK + 255) / 256, 256, 0, stream>>>(cb, cnorm);
    argmin_kernel<<<NB * NH, 256, 0, stream>>>(z, cb, cnorm, idx_ws, idx_out);
    gather_loss_kernel<<<NOUT / 1024, 256, 0, stream>>>(z, cb, idx_ws, out, loss_acc);
    finalize_kernel<<<1, 64, 0, stream>>>(loss_acc, loss_out);
}

// Round 4
// 1191.995 us; speedup vs baseline: 1.8584x; 1.8584x over previous
//
#include <hip/hip_runtime.h>

#define NB 16
#define NC 256
#define NH 64
#define NW 64
#define NK 1024
#define HW (NH * NW)          // 4096
#define NPOS (NB * HW)        // 65536
#define NOUT (NB * NC * HW)   // 16777216
#define ZSTR 258              // z_lds row stride: ==2 mod 4 -> 8B-aligned rows, bank stride 2 (free)

__device__ __forceinline__ float sq_rn(float x) { return __fmul_rn(x, x); }

// Exact replica of numpy pairwise_sum for sum(a*a) over n=256 (verified R2).
__device__ __forceinline__ float pairwise_sumsq_256(const float* __restrict__ a,
                                                    int stride) {
    float s_half[2];
#pragma unroll
    for (int h = 0; h < 2; ++h) {
        const float* base = a + (size_t)(h * 128) * stride;
        float r[8];
#pragma unroll
        for (int j = 0; j < 8; ++j) r[j] = sq_rn(base[(size_t)j * stride]);
        for (int i = 8; i < 128; i += 8) {
#pragma unroll
            for (int j = 0; j < 8; ++j)
                r[j] = __fadd_rn(r[j], sq_rn(base[(size_t)(i + j) * stride]));
        }
        s_half[h] = __fadd_rn(
            __fadd_rn(__fadd_rn(r[0], r[1]), __fadd_rn(r[2], r[3])),
            __fadd_rn(__fadd_rn(r[4], r[5]), __fadd_rn(r[6], r[7])));
    }
    return __fadd_rn(s_half[0], s_half[1]);
}

// ---------------------------------------------------------------------------
// Kernel A: cnorm[k] = numpy-fp32 sum(codebook[k]^2)
// ---------------------------------------------------------------------------
__global__ __launch_bounds__(256) void cnorm_kernel(const float* __restrict__ cb,
                                                    float* __restrict__ cnorm) {
    int k = blockIdx.x * 256 + threadIdx.x;
    if (k < NK) {
        cnorm[k] = pairwise_sumsq_256(cb + (size_t)k * NC, 1);
    }
}

// ---------------------------------------------------------------------------
// Kernel B (R4): LDS-fed fp32 GEMM argmin.
// Block: 256 thr = 4 waves; 128 positions (one b, h-pair hp). z staged once
// into z_lds[128][258] (bank-stride-2 = conflict-free divergent b64 reads).
// Waves split the 1024 codes 4-way; lane holds M=2 positions, Kt=32 codes.
// Codebook streams via wave-private 2KB LDS tiles (VGPR-prefetched, no
// barriers in the k-loop); consumed by same-address broadcast ds_reads.
// Bit-exact: acc[m][kk] is one sequential __fmaf_rn chain over ascending d;
// score = fl(fl(znorm+cnorm_k) - 2*dot); strict < ascending k (np.argmin).
// ---------------------------------------------------------------------------
__global__ __launch_bounds__(256, 1) void argmin_kernel(const float* __restrict__ z,
                                                        const float* __restrict__ cb,
                                                        const float* __restrict__ cnorm,
                                                        int* __restrict__ idx_ws,
                                                        float* __restrict__ idx_out) {
    __shared__ float z_lds[128][ZSTR];    // 132,096 B
    __shared__ float cb_lds[4][32][16];   //   8,192 B (2 KB per wave)
    __shared__ float rv[4][128];          //   2,048 B
    __shared__ int   ri[4][128];          //   2,048 B   -> 144,384 B total

    const int blk = blockIdx.x;           // 0..511
    const int b = blk >> 5;               // 0..15
    const int hp = blk & 31;              // h-pair: rows 2hp, 2hp+1
    const int t = threadIdx.x;
    const int lane = t & 63;
    const int wave = t >> 6;

    // ---- stage z (coalesced global, bank-stride-2 LDS writes) ----
    {
        const int c_off = t >> 7;         // 0..1
        const int pos = t & 127;
        const float* zg = z + (size_t)b * (NC * HW) + (size_t)hp * 128 + pos;
#pragma unroll 4
        for (int i = 0; i < 128; ++i) {
            const int c = i * 2 + c_off;
            z_lds[pos][c] = zg[(size_t)c * HW];
        }
    }
    __syncthreads();

    // numpy-exact znorm for this lane's two positions (same bits as global z)
    float znorm[2];
    znorm[0] = pairwise_sumsq_256(&z_lds[lane][0], 1);
    znorm[1] = pairwise_sumsq_256(&z_lds[64 + lane][0], 1);

    float best[2] = {3.4e38f, 3.4e38f};
    int bidx[2] = {0, 0};

    const int kw0 = wave * 256;
    const int kl = lane >> 1;             // code slot this lane stages (0..31)
    const int dl = (lane & 1) * 8;        // dim offset this lane stages (0/8)

#pragma unroll 1
    for (int pass = 0; pass < 8; ++pass) {
        const int k0 = kw0 + pass * 32;
        const float* cbg = cb + (size_t)k0 * NC;

        float acc[2][32];
#pragma unroll
        for (int m = 0; m < 2; ++m)
#pragma unroll
            for (int i = 0; i < 32; ++i) acc[m][i] = 0.f;

        // prefetch sub-tile 0 (16 dims x 32 codes; lane stages 8 floats)
        float4 pf0 = *(const float4*)(cbg + (size_t)kl * NC + dl);
        float4 pf1 = *(const float4*)(cbg + (size_t)kl * NC + dl + 4);

#pragma unroll 1
        for (int s = 0; s < 16; ++s) {
            // commit prefetched tile to this wave's private LDS buffer
            *(float4*)&cb_lds[wave][kl][dl] = pf0;
            *(float4*)&cb_lds[wave][kl][dl + 4] = pf1;
            if (s < 15) {
                pf0 = *(const float4*)(cbg + (size_t)kl * NC + (s + 1) * 16 + dl);
                pf1 = *(const float4*)(cbg + (size_t)kl * NC + (s + 1) * 16 + dl + 4);
            }
            // compute on tile s: dims dg = s*16 + {0..15}
#pragma unroll
            for (int ch = 0; ch < 2; ++ch) {
                const int dg = s * 16 + ch * 8;
                float vz[2][8];
#pragma unroll
                for (int m = 0; m < 2; ++m) {
                    const float* zp = &z_lds[m * 64 + lane][dg];
#pragma unroll
                    for (int jj = 0; jj < 4; ++jj) {
                        const float2 q = *(const float2*)(zp + jj * 2);
                        vz[m][jj * 2] = q.x;
                        vz[m][jj * 2 + 1] = q.y;
                    }
                }
#pragma unroll
                for (int kk = 0; kk < 32; ++kk) {
                    const float4 c0 = *(const float4*)&cb_lds[wave][kk][ch * 8];
                    const float4 c1 = *(const float4*)&cb_lds[wave][kk][ch * 8 + 4];
#pragma unroll
                    for (int m = 0; m < 2; ++m) {
                        float a = acc[m][kk];
                        a = __fmaf_rn(vz[m][0], c0.x, a);
                        a = __fmaf_rn(vz[m][1], c0.y, a);
                        a = __fmaf_rn(vz[m][2], c0.z, a);
                        a = __fmaf_rn(vz[m][3], c0.w, a);
                        a = __fmaf_rn(vz[m][4], c1.x, a);
                        a = __fmaf_rn(vz[m][5], c1.y, a);
                        a = __fmaf_rn(vz[m][6], c1.z, a);
                        a = __fmaf_rn(vz[m][7], c1.w, a);
                        acc[m][kk] = a;
                    }
                }
            }
        }

        // scores for this pass's 32 codes
#pragma unroll
        for (int kk = 0; kk < 32; ++kk) {
            const int k = k0 + kk;
            const float cn = cnorm[k];
#pragma unroll
            for (int m = 0; m < 2; ++m) {
                const float sc = __fsub_rn(__fadd_rn(znorm[m], cn),
                                           __fmul_rn(2.0f, acc[m][kk]));
                if (sc < best[m]) {       // ascending k -> first-occurrence ties
                    best[m] = sc;
                    bidx[m] = k;
                }
            }
        }
    }

    // cross-wave reduce (waves hold disjoint ascending code ranges)
    rv[wave][lane] = best[0];
    ri[wave][lane] = bidx[0];
    rv[wave][64 + lane] = best[1];
    ri[wave][64 + lane] = bidx[1];
    __syncthreads();

    if (t < 128) {
        float bv = rv[0][t];
        int bi = ri[0][t];
#pragma unroll
        for (int w = 1; w < 4; ++w) {
            const float v = rv[w][t];
            const int i2 = ri[w][t];
            if (v < bv) {                 // ascending wave -> lowest k on ties
                bv = v;
                bi = i2;
            }
        }
        const int pglob = b * HW + hp * 128 + t;
        idx_ws[pglob] = bi;
        idx_out[pglob] = (float)bi;
    }
}

// ---------------------------------------------------------------------------
// Kernel C: out[b,c,h,w] = cb[idx[b,h,w]][c]; accumulate sum((zq - z)^2)
// ---------------------------------------------------------------------------
__global__ __launch_bounds__(256) void gather_loss_kernel(const float* __restrict__ z,
                                                          const float* __restrict__ cb,
                                                          const int* __restrict__ idx_ws,
                                                          float* __restrict__ out,
                                                          double* __restrict__ loss_acc) {
    const unsigned g = blockIdx.x * 256u + threadIdx.x;  // float4 index
    const unsigned e = g * 4u;                           // element index
    const unsigned w = e & 63u;
    const unsigned h = (e >> 6) & 63u;
    const unsigned c = (e >> 12) & 255u;
    const unsigned b = e >> 20;

    const unsigned p = b * HW + h * NW + w;  // divisible by 4

    const int4 iv = *(const int4*)(idx_ws + p);
    const float4 z4 = *(const float4*)(z + e);

    float4 o;
    o.x = cb[(size_t)iv.x * NC + c];
    o.y = cb[(size_t)iv.y * NC + c];
    o.z = cb[(size_t)iv.z * NC + c];
    o.w = cb[(size_t)iv.w * NC + c];

    *(float4*)(out + e) = o;

    const float d0 = o.x - z4.x;
    const float d1 = o.y - z4.y;
    const float d2 = o.z - z4.z;
    const float d3 = o.w - z4.w;
    float part = d0 * d0 + d1 * d1 + d2 * d2 + d3 * d3;

#pragma unroll
    for (int off = 32; off > 0; off >>= 1) part += __shfl_down(part, off, 64);

    __shared__ float wsum[4];
    const int lane = threadIdx.x & 63;
    const int wave = threadIdx.x >> 6;
    if (lane == 0) wsum[wave] = part;
    __syncthreads();
    if (threadIdx.x == 0) {
        float s = wsum[0] + wsum[1] + wsum[2] + wsum[3];
        atomicAdd(loss_acc, (double)s);
    }
}

// ---------------------------------------------------------------------------
// Kernel D: loss = (1 + beta) * sum / NOUT
// ---------------------------------------------------------------------------
__global__ void finalize_kernel(const double* __restrict__ loss_acc,
                                float* __restrict__ out_loss) {
    if (threadIdx.x == 0) {
        *out_loss = (float)(1.25 * (*loss_acc) / (double)NOUT);
    }
}

extern "C" void kernel_launch(void* const* d_in, const int* in_sizes, int n_in,
                              void* d_out, int out_size, void* d_ws, size_t ws_size,
                              hipStream_t stream) {
    const float* z = (const float*)d_in[0];
    const float* cb = (const float*)d_in[1];

    float* out = (float*)d_out;            // [16,256,64,64]
    float* loss_out = out + NOUT;          // scalar
    float* idx_out = out + NOUT + 1;       // [16,1,64,64] as float

    double* loss_acc = (double*)d_ws;                      // 8 B (zeroed below)
    float* cnorm = (float*)((char*)d_ws + 64);             // 4 KB
    int* idx_ws = (int*)((char*)d_ws + 64 + NK * 4);       // 256 KB

    hipMemsetAsync(d_ws, 0, 64, stream);
    cnorm_kernel<<<(NK + 255) / 256, 256, 0, stream>>>(cb, cnorm);
    argmin_kernel<<<NPOS / 128, 256, 0, stream>>>(z, cb, cnorm, idx_ws, idx_out);
    gather_loss_kernel<<<NOUT / 1024, 256, 0, stream>>>(z, cb, idx_ws, out, loss_acc);
    finalize_kernel<<<1, 64, 0, stream>>>(loss_acc, loss_out);
}

// Round 6
// 715.055 us; speedup vs baseline: 3.0980x; 1.6670x over previous
//
#include <hip/hip_runtime.h>

#define NB 16
#define NC 256
#define NH 64
#define NW 64
#define NK 1024
#define HW (NH * NW)          // 4096
#define NPOS (NB * HW)        // 65536
#define NOUT (NB * NC * HW)   // 16777216
#define CBSTR 260             // cb_lds row stride (floats): 16B-aligned rows, <=2-way banks

__device__ __forceinline__ float sq_rn(float x) { return __fmul_rn(x, x); }

// Exact replica of numpy pairwise_sum for sum(a*a) over n=256 (verified R2/R4).
__device__ __forceinline__ float pairwise_sumsq_256(const float* __restrict__ a,
                                                    int stride) {
    float s_half[2];
#pragma unroll
    for (int h = 0; h < 2; ++h) {
        const float* base = a + (size_t)(h * 128) * stride;
        float r[8];
#pragma unroll
        for (int j = 0; j < 8; ++j) r[j] = sq_rn(base[(size_t)j * stride]);
        for (int i = 8; i < 128; i += 8) {
#pragma unroll
            for (int j = 0; j < 8; ++j)
                r[j] = __fadd_rn(r[j], sq_rn(base[(size_t)(i + j) * stride]));
        }
        s_half[h] = __fadd_rn(
            __fadd_rn(__fadd_rn(r[0], r[1]), __fadd_rn(r[2], r[3])),
            __fadd_rn(__fadd_rn(r[4], r[5]), __fadd_rn(r[6], r[7])));
    }
    return __fadd_rn(s_half[0], s_half[1]);
}

// ---------------------------------------------------------------------------
// Kernel A: cnorm[k] = numpy-fp32 sum(codebook[k]^2)
// ---------------------------------------------------------------------------
__global__ __launch_bounds__(256) void cnorm_kernel(const float* __restrict__ cb,
                                                    float* __restrict__ cnorm) {
    int k = blockIdx.x * 256 + threadIdx.x;
    if (k < NK) {
        cnorm[k] = pairwise_sumsq_256(cb + (size_t)k * NC, 1);
    }
}

// ---------------------------------------------------------------------------
// Kernel B (R6 = R5 + tie-break fix): 8x8 register-tiled fp32 GEMM argmin.
// Block: 256 thr = 4 waves; 64 positions (one h-row). z d-major in LDS
// (z_lds[256][64], 64 KB, staged once). Codes: wave w owns [w*256,w*256+256),
// 4 passes of 64; lane = 8 pos-groups x 8 code-groups; thread acc[8][8].
// cb streamed transposed in 8-dim slices (cb_lds[8][260]) with VGPR prefetch.
// R5 BUG: cross-cg k-ranges interleave across passes, so the strict-< shuffle
// reduce broke np.argmin first-occurrence on exact fp32 ties. Fixed with an
// explicit lower-index tie-break in both reduce stages.
// Bit-exact: acc = one sequential __fmaf_rn chain over ascending d;
// score = fl(fl(znorm+cnorm) - 2*dot).
// ---------------------------------------------------------------------------
__global__ __launch_bounds__(256, 2) void argmin_kernel(const float* __restrict__ z,
                                                        const float* __restrict__ cb,
                                                        const float* __restrict__ cnorm,
                                                        int* __restrict__ idx_ws,
                                                        float* __restrict__ idx_out) {
    __shared__ float z_lds[256][64];      // 65536 B, [d][p]
    __shared__ float cb_lds[8][CBSTR];    //  8320 B, [d_local][code_local 0..255]
    __shared__ float znorm_s[64];         //   256 B
    __shared__ float red_v[4][64];        //  1024 B
    __shared__ int   red_i[4][64];        //  1024 B   -> 76160 B total

    const int blk = blockIdx.x;           // 0..1023
    const int b = blk >> 6;               // batch
    const int hw0 = (blk & 63) * 64;      // h-row base (64 contiguous positions)
    const int t = threadIdx.x;
    const int lane = t & 63;
    const int wave = t >> 6;              // 0..3
    const int pg = lane & 7;              // position group (8 pos each)
    const int cg = lane >> 3;             // code group (8 codes each)

    const float* zg = z + (size_t)b * (NC * HW) + hw0;

    // ---- stage z d-major: 16 iters of float4 (coalesced; <=2-way LDS banks)
#pragma unroll 4
    for (int i = 0; i < 16; ++i) {
        const int flat4 = i * 1024 + t * 4;   // multiple of 4
        const int d = flat4 >> 6;
        const int p = flat4 & 63;
        const float4 v = *(const float4*)(zg + (size_t)d * HW + p);
        *(float4*)&z_lds[d][p] = v;
    }
    // numpy-exact znorm (same global-strided code path verified in R2/R4)
    if (wave == 0) znorm_s[lane] = pairwise_sumsq_256(zg + lane, HW);
    __syncthreads();

    float zn[8];
#pragma unroll
    for (int i = 0; i < 8; ++i) zn[i] = znorm_s[pg * 8 + i];

    float best[8];
    int bid[8];
#pragma unroll
    for (int i = 0; i < 8; ++i) { best[i] = 3.4e38f; bid[i] = 0; }

#pragma unroll 1
    for (int pass = 0; pass < 4; ++pass) {
        float acc[8][8];
#pragma unroll
        for (int i = 0; i < 8; ++i)
#pragma unroll
            for (int j = 0; j < 8; ++j) acc[i][j] = 0.f;

        // thread t stages code (t>>6)*256 + pass*64 + (t&63) into column t
        const int kstage = (t >> 6) * 256 + pass * 64 + (t & 63);
        const float* cbg = cb + (size_t)kstage * NC;

        float4 pf0 = *(const float4*)(cbg);
        float4 pf1 = *(const float4*)(cbg + 4);

#pragma unroll 1
        for (int sl = 0; sl < 32; ++sl) {
            __syncthreads();              // previous slice's compute done
            cb_lds[0][t] = pf0.x;
            cb_lds[1][t] = pf0.y;
            cb_lds[2][t] = pf0.z;
            cb_lds[3][t] = pf0.w;
            cb_lds[4][t] = pf1.x;
            cb_lds[5][t] = pf1.y;
            cb_lds[6][t] = pf1.z;
            cb_lds[7][t] = pf1.w;
            if (sl < 31) {                // prefetch next slice (hides latency)
                pf0 = *(const float4*)(cbg + (sl + 1) * 8);
                pf1 = *(const float4*)(cbg + (sl + 1) * 8 + 4);
            }
            __syncthreads();              // staging visible

            const int ds = sl * 8;
#pragma unroll
            for (int dl = 0; dl < 8; ++dl) {
                const int d = ds + dl;
                const float4 za = *(const float4*)&z_lds[d][pg * 8];
                const float4 zb = *(const float4*)&z_lds[d][pg * 8 + 4];
                const float4 ca = *(const float4*)&cb_lds[dl][wave * 64 + cg * 8];
                const float4 cc = *(const float4*)&cb_lds[dl][wave * 64 + cg * 8 + 4];
                const float zf[8] = {za.x, za.y, za.z, za.w, zb.x, zb.y, zb.z, zb.w};
                const float cf[8] = {ca.x, ca.y, ca.z, ca.w, cc.x, cc.y, cc.z, cc.w};
#pragma unroll
                for (int i = 0; i < 8; ++i)
#pragma unroll
                    for (int j = 0; j < 8; ++j)
                        acc[i][j] = __fmaf_rn(zf[i], cf[j], acc[i][j]);
            }
        }

        // scores for this pass's 8 codes of this thread (k ascending within
        // thread across passes -> strict < keeps first occurrence)
        const int k0 = wave * 256 + pass * 64 + cg * 8;
        const float4 cn0 = *(const float4*)(cnorm + k0);
        const float4 cn1 = *(const float4*)(cnorm + k0 + 4);
        const float cnf[8] = {cn0.x, cn0.y, cn0.z, cn0.w, cn1.x, cn1.y, cn1.z, cn1.w};
#pragma unroll
        for (int j = 0; j < 8; ++j) {
            const int k = k0 + j;
#pragma unroll
            for (int i = 0; i < 8; ++i) {
                const float sc = __fsub_rn(__fadd_rn(zn[i], cnf[j]),
                                           __fmul_rn(2.0f, acc[i][j]));
                if (sc < best[i]) { best[i] = sc; bid[i] = k; }
            }
        }
    }

    // ---- reduce across cg (lane stride 8). k-ranges of different cg lanes
    //      INTERLEAVE across passes -> must tie-break on lower index to match
    //      np.argmin first-occurrence (R5 bug).
#pragma unroll
    for (int off = 32; off >= 8; off >>= 1) {
#pragma unroll
        for (int i = 0; i < 8; ++i) {
            const float v = __shfl_down(best[i], off, 64);
            const int d2 = __shfl_down(bid[i], off, 64);
            if (v < best[i] || (v == best[i] && d2 < bid[i])) {
                best[i] = v;
                bid[i] = d2;
            }
        }
    }
    if (cg == 0) {
#pragma unroll
        for (int i = 0; i < 8; ++i) {
            red_v[wave][pg * 8 + i] = best[i];
            red_i[wave][pg * 8 + i] = bid[i];
        }
    }
    __syncthreads();

    // ---- final reduce across waves (disjoint ascending k ranges; index
    //      tie-break kept anyway for safety)
    if (t < 64) {
        float bv = red_v[0][t];
        int bi = red_i[0][t];
#pragma unroll
        for (int w = 1; w < 4; ++w) {
            const float v = red_v[w][t];
            const int i2 = red_i[w][t];
            if (v < bv || (v == bv && i2 < bi)) { bv = v; bi = i2; }
        }
        const int g = b * HW + hw0 + t;
        idx_ws[g] = bi;
        idx_out[g] = (float)bi;
    }
}

// ---------------------------------------------------------------------------
// Kernel C: out[b,c,h,w] = cb[idx[b,h,w]][c]; accumulate sum((zq - z)^2)
// ---------------------------------------------------------------------------
__global__ __launch_bounds__(256) void gather_loss_kernel(const float* __restrict__ z,
                                                          const float* __restrict__ cb,
                                                          const int* __restrict__ idx_ws,
                                                          float* __restrict__ out,
                                                          double* __restrict__ loss_acc) {
    const unsigned g = blockIdx.x * 256u + threadIdx.x;  // float4 index
    const unsigned e = g * 4u;                           // element index
    const unsigned w = e & 63u;
    const unsigned h = (e >> 6) & 63u;
    const unsigned c = (e >> 12) & 255u;
    const unsigned b = e >> 20;

    const unsigned p = b * HW + h * NW + w;  // divisible by 4

    const int4 iv = *(const int4*)(idx_ws + p);
    const float4 z4 = *(const float4*)(z + e);

    float4 o;
    o.x = cb[(size_t)iv.x * NC + c];
    o.y = cb[(size_t)iv.y * NC + c];
    o.z = cb[(size_t)iv.z * NC + c];
    o.w = cb[(size_t)iv.w * NC + c];

    *(float4*)(out + e) = o;

    const float d0 = o.x - z4.x;
    const float d1 = o.y - z4.y;
    const float d2 = o.z - z4.z;
    const float d3 = o.w - z4.w;
    float part = d0 * d0 + d1 * d1 + d2 * d2 + d3 * d3;

#pragma unroll
    for (int off = 32; off > 0; off >>= 1) part += __shfl_down(part, off, 64);

    __shared__ float wsum[4];
    const int lane = threadIdx.x & 63;
    const int wave = threadIdx.x >> 6;
    if (lane == 0) wsum[wave] = part;
    __syncthreads();
    if (threadIdx.x == 0) {
        float s = wsum[0] + wsum[1] + wsum[2] + wsum[3];
        atomicAdd(loss_acc, (double)s);
    }
}

// ---------------------------------------------------------------------------
// Kernel D: loss = (1 + beta) * sum / NOUT
// ---------------------------------------------------------------------------
__global__ void finalize_kernel(const double* __restrict__ loss_acc,
                                float* __restrict__ out_loss) {
    if (threadIdx.x == 0) {
        *out_loss = (float)(1.25 * (*loss_acc) / (double)NOUT);
    }
}

extern "C" void kernel_launch(void* const* d_in, const int* in_sizes, int n_in,
                              void* d_out, int out_size, void* d_ws, size_t ws_size,
                              hipStream_t stream) {
    const float* z = (const float*)d_in[0];
    const float* cb = (const float*)d_in[1];

    float* out = (float*)d_out;            // [16,256,64,64]
    float* loss_out = out + NOUT;          // scalar
    float* idx_out = out + NOUT + 1;       // [16,1,64,64] as float

    double* loss_acc = (double*)d_ws;                      // 8 B (zeroed below)
    float* cnorm = (float*)((char*)d_ws + 64);             // 4 KB
    int* idx_ws = (int*)((char*)d_ws + 64 + NK * 4);       // 256 KB

    hipMemsetAsync(d_ws, 0, 64, stream);
    cnorm_kernel<<<(NK + 255) / 256, 256, 0, stream>>>(cb, cnorm);
    argmin_kernel<<<NPOS / 64, 256, 0, stream>>>(z, cb, cnorm, idx_ws, idx_out);
    gather_loss_kernel<<<NOUT / 1024, 256, 0, stream>>>(z, cb, idx_ws, out, loss_acc);
    finalize_kernel<<<1, 64, 0, stream>>>(loss_acc, loss_out);
}